// Round 3
// baseline (316.975 us; speedup 1.0000x reference)
//
#include <hip/hip_runtime.h>
#include <math.h>

#define NORB 13
#define NORB2 (NORB * NORB)
#define NTHR 832               // 13 waves; thread = 2 adjacent complex columns
#define MAXE 256               // entries incident to one atom (mean ~32)

typedef float fx2 __attribute__((ext_vector_type(2)));
typedef float fx4 __attribute__((ext_vector_type(4)));

// block id per orbital index for L_LIST=[0,0,1,1,2] -> sizes 1,1,3,3,5
__device__ __forceinline__ int blk_of(int p) {
    return p < 1 ? 0 : (p < 2 ? 1 : (p < 5 ? 2 : (p < 8 ? 3 : 4)));
}
__device__ __forceinline__ float bfac(int bp, int bq) {
    return bp < bq ? 1.0f : (bp == bq ? 0.5f : 0.0f);
}

// One WG per (k, a). The WG owns the contiguous 173 KB row-block
// out[k, a*13 .. a*13+12, :]; stores are fully sequential per WG.
__global__ void __launch_bounds__(NTHR)
k_fused(const float* __restrict__ hopping,
        const float* __restrict__ onsite,
        const float* __restrict__ kpoints,
        const float* __restrict__ cell_shift,
        const int* __restrict__ edge_index,
        float* __restrict__ out,
        int N, int E, int K, int ld, int es) {
    int a = blockIdx.x % N;
    int k = blockIdx.x / N;
    int tid = threadIdx.x;

    __shared__ int ecnt;
    __shared__ int   elist[MAXE];   // (e<<8) | (b<<1) | rev
    __shared__ float phc[MAXE];     // cos
    __shared__ float phs[MAXE];     // sin, sign-folded for rev (conj)

    if (tid == 0) ecnt = 0;
    __syncthreads();

    // scan tiny edge list (16 KB, L2-hot) for all edges incident to atom a
    for (int e = tid; e < E; e += NTHR) {
        int ie = edge_index[e], je = edge_index[E + e];
        if (ie == a) { int pos = atomicAdd(&ecnt, 1);
                       if (pos < MAXE) elist[pos] = (e << 8) | (je << 1); }
        if (je == a) { int pos = atomicAdd(&ecnt, 1);
                       if (pos < MAXE) elist[pos] = (e << 8) | (ie << 1) | 1; }
    }
    __syncthreads();
    int nent = min(__builtin_amdgcn_readfirstlane(ecnt), MAXE);

    // phases for this WG's single k (once; no sincos in the hot loop)
    float kx = kpoints[3 * k], ky = kpoints[3 * k + 1], kz = kpoints[3 * k + 2];
    for (int t = tid; t < nent; t += NTHR) {
        int ent = elist[t];
        int e = ent >> 8;
        float d = kx * cell_shift[3 * e] + ky * cell_shift[3 * e + 1]
                + kz * cell_shift[3 * e + 2];
        float s, c;
        __sincosf(-6.2831853071795864f * d, &s, &c);   // exp(-i*2pi*d) = c + i*s
        phc[t] = c;
        phs[t] = (ent & 1) ? -s : s;                   // conj for reverse
    }
    __syncthreads();

    // broadcast first 64 entries into registers: lane l holds entry l
    int lane = tid & 63;
    int   bent = (lane < nent) ? elist[lane] : 0;
    float bc   = (lane < nent) ? phc[lane]  : 0.f;
    float bs   = (lane < nent) ? phs[lane]  : 0.f;

    // this thread's two columns
    int c0 = 2 * tid, c1 = c0 + 1;           // < 1664 always
    int b0a = c0 / NORB, q0 = c0 - NORB * b0a;
    int b1a = c1 / NORB, q1 = c1 - NORB * b1a;
    int bq0 = blk_of(q0), bq1 = blk_of(q1);

    // accumulators: 13 rows x 2 cols, statically indexed
    float a0x[NORB], a0y[NORB], a1x[NORB], a1y[NORB];
    const float* on = onsite + (size_t)a * NORB2;
    #pragma unroll
    for (int p = 0; p < NORB; ++p) {
        int bp = blk_of(p);                  // compile-time per unrolled p
        float v0 = 0.f, v1 = 0.f;
        if (b0a == a) v0 = on[p * NORB + q0] * bfac(bp, bq0)
                         + on[q0 * NORB + p] * bfac(bq0, bp);
        if (b1a == a) v1 = on[p * NORB + q1] * bfac(bp, bq1)
                         + on[q1 * NORB + p] * bfac(bq1, bp);
        a0x[p] = v0; a0y[p] = 0.f;
        a1x[p] = v1; a1y[p] = 0.f;
    }

    // entry loop: uniform skip for non-matching entries (execz fast path)
    for (int it = 0; it < nent; ++it) {
        int ent; float cc, ss;
        if (it < 64) {
            ent = __builtin_amdgcn_readlane(bent, it);
            cc  = __int_as_float(__builtin_amdgcn_readlane(__float_as_int(bc), it));
            ss  = __int_as_float(__builtin_amdgcn_readlane(__float_as_int(bs), it));
        } else {                              // rare tail (nent > 64)
            ent = elist[it]; cc = phc[it]; ss = phs[it];
        }
        int bb  = (ent >> 1) & 127;
        int rev = ent & 1;
        const float* h = hopping + (size_t)(ent >> 8) * NORB2;
        if (b0a == bb) {
            #pragma unroll
            for (int p = 0; p < NORB; ++p) {
                int bp = blk_of(p);
                float hv = rev ? h[q0 * NORB + p] * bfac(bq0, bp)
                               : h[p * NORB + q0] * bfac(bp, bq0);
                a0x[p] += cc * hv; a0y[p] += ss * hv;
            }
        }
        if (b1a == bb) {
            #pragma unroll
            for (int p = 0; p < NORB; ++p) {
                int bp = blk_of(p);
                float hv = rev ? h[q1 * NORB + p] * bfac(bq1, bp)
                               : h[p * NORB + q1] * bfac(bp, bq1);
                a1x[p] += cc * hv; a1y[p] += ss * hv;
            }
        }
    }

    // stores: row p is 13312 B covered contiguously by the 13 waves;
    // rows are consecutive -> the WG writes one 173 KB sequential region
    size_t rowbase = ((size_t)(k * ld + a * NORB)) * ld;   // complex units
    if (es == 2) {
        fx4* o4 = (fx4*)out;
        #pragma unroll
        for (int p = 0; p < NORB; ++p) {
            size_t ci = rowbase + (size_t)p * ld + c0;     // even
            o4[ci >> 1] = (fx4){a0x[p], a0y[p], a1x[p], a1y[p]};
        }
    } else {
        fx2* o2 = (fx2*)out;
        #pragma unroll
        for (int p = 0; p < NORB; ++p) {
            size_t ci = rowbase + (size_t)p * ld + c0;
            o2[ci >> 1] = (fx2){a0x[p], a1x[p]};
        }
    }
}

extern "C" void kernel_launch(void* const* d_in, const int* in_sizes, int n_in,
                              void* d_out, int out_size, void* d_ws, size_t ws_size,
                              hipStream_t stream) {
    const float* hopping    = (const float*)d_in[0];
    const float* onsite     = (const float*)d_in[1];
    const float* kpoints    = (const float*)d_in[2];
    const float* cell_shift = (const float*)d_in[3];
    const int*   edge_index = (const int*)d_in[4];
    float* out = (float*)d_out;

    int E = in_sizes[0] / NORB2;   // 2048
    int N = in_sizes[1] / NORB2;   // 128
    int K = in_sizes[2] / 3;       // 16
    int ld = N * NORB;             // 1664

    size_t full = (size_t)K * ld * ld * 2;
    int es = ((size_t)out_size >= full) ? 2 : 1;

    int nwg = N * K;               // 2048 WGs, one 173 KB sequential block each
    k_fused<<<nwg, NTHR, 0, stream>>>(hopping, onsite, kpoints, cell_shift,
                                      edge_index, out, N, E, K, ld, es);
}

// Round 5
// 239.639 us; speedup vs baseline: 1.3227x; 1.3227x over previous
//
#include <hip/hip_runtime.h>
#include <math.h>

#define NORB 13
#define NORB2 (NORB * NORB)
#define NTHR 256
#define MAXE 256               // entries incident to one atom (mean ~32)
#define NBIN 128               // partner-atom bins (N <= 128)

typedef float fx2 __attribute__((ext_vector_type(2)));
typedef float fx4 __attribute__((ext_vector_type(4)));

// block id per orbital index for L_LIST=[0,0,1,1,2] -> sizes 1,1,3,3,5
__device__ __forceinline__ int blk_of(int p) {
    return p < 1 ? 0 : (p < 2 ? 1 : (p < 5 ? 2 : (p < 8 ? 3 : 4)));
}
__device__ __forceinline__ float bfac(int bp, int bq) {
    return bp < bq ? 1.0f : (bp == bq ? 0.5f : 0.0f);
}

// One WG per (k, a): owns the contiguous 173 KB row-block out[k, a*13.., :].
// 256 threads, 4 waves, no barriers in the main loop; stores are 4 KB/instr
// and strictly sequential over the whole region (fill-like stream).
__global__ void __launch_bounds__(NTHR)
k_fused(const float* __restrict__ hopping,
        const float* __restrict__ onsite,
        const float* __restrict__ kpoints,
        const float* __restrict__ cell_shift,
        const int* __restrict__ edge_index,
        float* __restrict__ out,
        int N, int E, int K, int ld, int es) {
    int a = blockIdx.x % N;
    int k = blockIdx.x / N;
    int tid = threadIdx.x;

    __shared__ int   boff[NBIN + 1];   // counts -> CSR offsets
    __shared__ int   cur[NBIN];        // placement cursors
    __shared__ int   elist[MAXE];      // (e<<8) | (b<<1) | rev, sorted by b
    __shared__ float phc[MAXE];        // cos
    __shared__ float phs[MAXE];        // sin (sign-folded: conj for rev)

    if (tid < NBIN) boff[tid] = 0;
    __syncthreads();

    // count entries per partner atom b (edges incident to a; 16 KB list, L2-hot)
    for (int e = tid; e < E; e += NTHR) {
        int ie = edge_index[e], je = edge_index[E + e];
        if (ie == a) atomicAdd(&boff[je], 1);
        if (je == a) atomicAdd(&boff[ie], 1);
    }
    __syncthreads();

    // exclusive prefix over 128 bins: wave 0, 2 bins/lane, shfl scan
    if (tid < 64) {
        int v0 = boff[2 * tid], v1 = boff[2 * tid + 1];
        int s = v0 + v1, sc = s;
        #pragma unroll
        for (int d = 1; d < 64; d <<= 1) {
            int t = __shfl_up(sc, d);
            if (tid >= d) sc += t;
        }
        int excl = sc - s;
        boff[2 * tid] = excl;       cur[2 * tid] = excl;
        boff[2 * tid + 1] = excl + v0; cur[2 * tid + 1] = excl + v0;
        if (tid == 63) boff[NBIN] = sc;
    }
    __syncthreads();

    // place entries (counting sort by b)
    for (int e = tid; e < E; e += NTHR) {
        int ie = edge_index[e], je = edge_index[E + e];
        if (ie == a) {
            int pos = atomicAdd(&cur[je], 1);
            if (pos < MAXE) elist[pos] = (e << 8) | (je << 1);        // fwd
        }
        if (je == a) {
            int pos = atomicAdd(&cur[ie], 1);
            if (pos < MAXE) elist[pos] = (e << 8) | (ie << 1) | 1;    // rev
        }
    }
    __syncthreads();
    int nent = min(boff[NBIN], MAXE);

    // phases for this WG's single k (no sincos in the main loop)
    float kx = kpoints[3 * k], ky = kpoints[3 * k + 1], kz = kpoints[3 * k + 2];
    for (int t = tid; t < nent; t += NTHR) {
        int ent = elist[t];
        int e = ent >> 8;
        float d = kx * cell_shift[3 * e] + ky * cell_shift[3 * e + 1]
                + kz * cell_shift[3 * e + 2];
        float s, c;
        __sincosf(-6.2831853071795864f * d, &s, &c);   // exp(-i*2pi*d) = c + i*s
        phc[t] = c;
        phs[t] = (ent & 1) ? -s : s;                   // conj for reverse
    }
    __syncthreads();

    const float* on = onsite + (size_t)a * NORB2;
    size_t rb = (size_t)(k * ld + a * NORB) * ld;      // complex idx, row p=0
    int nch = (ld + 511) >> 9;                         // 512-col chunks (4)

    #pragma unroll 1
    for (int p = 0; p < NORB; ++p) {
        int bp = blk_of(p);
        #pragma unroll 1
        for (int ch = 0; ch < nch; ++ch) {
            int c0 = (ch << 9) + 2 * tid;
            if (c0 >= ld) continue;
            float vx[2], vy[2];
            #pragma unroll
            for (int u = 0; u < 2; ++u) {
                int c = c0 + u;
                int b = c / NORB, q = c - NORB * b;
                int bq = blk_of(q);
                float fpq = bfac(bp, bq), fqp = bfac(bq, bp);
                float ax = 0.f, ay = 0.f;
                if (b == a)                             // hermitized onsite
                    ax = on[p * NORB + q] * fpq + on[q * NORB + p] * fqp;
                int i0 = boff[b], i1 = boff[b + 1];
                if (i1 > MAXE) i1 = MAXE;
                for (int it = i0; it < i1; ++it) {
                    int ent = elist[it];
                    const float* h = hopping + (size_t)(ent >> 8) * NORB2;
                    float hv = (ent & 1) ? h[q * NORB + p] * fqp
                                         : h[p * NORB + q] * fpq;
                    ax += phc[it] * hv;
                    ay += phs[it] * hv;
                }
                vx[u] = ax; vy[u] = ay;
            }
            size_t ci = rb + (size_t)p * ld + c0;       // even
            if (es == 2) {
                ((fx4*)out)[ci >> 1] = (fx4){vx[0], vy[0], vx[1], vy[1]};
            } else {
                ((fx2*)out)[ci >> 1] = (fx2){vx[0], vx[1]};
            }
        }
    }
}

extern "C" void kernel_launch(void* const* d_in, const int* in_sizes, int n_in,
                              void* d_out, int out_size, void* d_ws, size_t ws_size,
                              hipStream_t stream) {
    const float* hopping    = (const float*)d_in[0];
    const float* onsite     = (const float*)d_in[1];
    const float* kpoints    = (const float*)d_in[2];
    const float* cell_shift = (const float*)d_in[3];
    const int*   edge_index = (const int*)d_in[4];
    float* out = (float*)d_out;

    int E = in_sizes[0] / NORB2;   // 2048
    int N = in_sizes[1] / NORB2;   // 128
    int K = in_sizes[2] / 3;       // 16
    int ld = N * NORB;             // 1664

    size_t full = (size_t)K * ld * ld * 2;
    int es = ((size_t)out_size >= full) ? 2 : 1;

    int nwg = N * K;               // 2048 WGs, one sequential 173 KB block each
    k_fused<<<nwg, NTHR, 0, stream>>>(hopping, onsite, kpoints, cell_shift,
                                      edge_index, out, N, E, K, ld, es);
}

// Round 6
// 224.469 us; speedup vs baseline: 1.4121x; 1.0676x over previous
//
#include <hip/hip_runtime.h>
#include <math.h>

#define NORB 13
#define NORB2 (NORB * NORB)
#define NTHR 256
#define MAXE 256               // entries incident to one atom (mean ~32)
#define NBIN 128               // partner-atom bins (N <= 128)
#define CHW 512                // complex columns per chunk (256 thr x 2)

typedef float fx2 __attribute__((ext_vector_type(2)));
typedef float fx4 __attribute__((ext_vector_type(4)));

// block id per orbital index for L_LIST=[0,0,1,1,2] -> sizes 1,1,3,3,5
__device__ __forceinline__ int blk_of(int p) {
    return p < 1 ? 0 : (p < 2 ? 1 : (p < 5 ? 2 : (p < 8 ? 3 : 4)));
}
__device__ __forceinline__ float bfac(int bp, int bq) {
    return bp < bq ? 1.0f : (bp == bq ? 0.5f : 0.0f);
}

// One WG per (k, a): owns contiguous 173 KB row-block out[k, a*13.., :].
// Per-thread column state (b,q,bin range, diag) cached in registers once;
// main loop is pure {cheap VALU + rare tiny entry loop + sequential dwordx4
// stores}, p ascending x 4KB chunks ascending => fill-like write stream.
__global__ void __launch_bounds__(NTHR, 8)
k_fused(const float* __restrict__ hopping,
        const float* __restrict__ onsite,
        const float* __restrict__ kpoints,
        const float* __restrict__ cell_shift,
        const int* __restrict__ edge_index,
        float* __restrict__ out,
        int N, int E, int K, int ld, int es) {
    int a = blockIdx.x % N;
    int k = blockIdx.x / N;
    int tid = threadIdx.x;

    __shared__ int   boff[NBIN + 1];   // counts -> CSR offsets
    __shared__ int   cur[NBIN];        // placement cursors
    __shared__ int   elist[MAXE];      // (e<<8) | (b<<1) | rev, sorted by b
    __shared__ float phc[MAXE];        // cos
    __shared__ float phs[MAXE];        // sin (sign-folded: conj for rev)

    if (tid < NBIN) boff[tid] = 0;
    __syncthreads();

    // count entries per partner atom b (edge list is 16 KB, L2-hot)
    for (int e = tid; e < E; e += NTHR) {
        int ie = edge_index[e], je = edge_index[E + e];
        if (ie == a) atomicAdd(&boff[je], 1);
        if (je == a) atomicAdd(&boff[ie], 1);
    }
    __syncthreads();

    // exclusive prefix over 128 bins: wave 0, 2 bins/lane, shfl scan
    if (tid < 64) {
        int v0 = boff[2 * tid], v1 = boff[2 * tid + 1];
        int s = v0 + v1, sc = s;
        #pragma unroll
        for (int d = 1; d < 64; d <<= 1) {
            int t = __shfl_up(sc, d);
            if (tid >= d) sc += t;
        }
        int excl = sc - s;
        boff[2 * tid] = excl;          cur[2 * tid] = excl;
        boff[2 * tid + 1] = excl + v0; cur[2 * tid + 1] = excl + v0;
        if (tid == 63) boff[NBIN] = sc;
    }
    __syncthreads();

    // place entries (counting sort by b)
    for (int e = tid; e < E; e += NTHR) {
        int ie = edge_index[e], je = edge_index[E + e];
        if (ie == a) {
            int pos = atomicAdd(&cur[je], 1);
            if (pos < MAXE) elist[pos] = (e << 8) | (je << 1);        // fwd
        }
        if (je == a) {
            int pos = atomicAdd(&cur[ie], 1);
            if (pos < MAXE) elist[pos] = (e << 8) | (ie << 1) | 1;    // rev
        }
    }
    __syncthreads();
    int nent = min(boff[NBIN], MAXE);

    // phases for this WG's single k (no sincos in the main loop)
    float kx = kpoints[3 * k], ky = kpoints[3 * k + 1], kz = kpoints[3 * k + 2];
    for (int t = tid; t < nent; t += NTHR) {
        int ent = elist[t];
        int e = ent >> 8;
        float d = kx * cell_shift[3 * e] + ky * cell_shift[3 * e + 1]
                + kz * cell_shift[3 * e + 2];
        float s, c;
        __sincosf(-6.2831853071795864f * d, &s, &c);   // exp(-i*2pi*d) = c + i*s
        phc[t] = c;
        phs[t] = (ent & 1) ? -s : s;                   // conj for reverse
    }
    __syncthreads();

    // ---- cache per-slot column state in registers (slot s = ch*2+u) ----
    int cq[8], cbq[8], ci0[8], ci1[8];
    unsigned dmask = 0;
    #pragma unroll
    for (int ch = 0; ch < 4; ++ch) {
        #pragma unroll
        for (int u = 0; u < 2; ++u) {
            int s = ch * 2 + u;
            int c = ch * CHW + 2 * tid + u;
            bool valid = (c < ld);
            int b = valid ? (c / NORB) : 0;
            int q = c - b * NORB;
            cq[s]  = q;
            cbq[s] = blk_of(q);
            int i0 = valid ? boff[b] : 0;
            int i1 = valid ? boff[b + 1] : 0;
            if (i1 > MAXE) i1 = MAXE;
            ci0[s] = i0; ci1[s] = i1;
            if (valid && b == a) dmask |= (1u << s);
        }
    }

    const float* on = onsite + (size_t)a * NORB2;
    size_t rb = (size_t)(k * ld + a * NORB) * ld;      // complex units

    #pragma unroll 1
    for (int p = 0; p < NORB; ++p) {
        int bp  = blk_of(p);
        int p13 = p * NORB;
        #pragma unroll
        for (int ch = 0; ch < 4; ++ch) {
            int c0 = ch * CHW + 2 * tid;
            if (c0 < ld) {
                float v[4];
                #pragma unroll
                for (int u = 0; u < 2; ++u) {
                    int s = ch * 2 + u;
                    int q = cq[s], bq = cbq[s];
                    float fpq = bfac(bp, bq), fqp = bfac(bq, bp);
                    float ax = 0.f, ay = 0.f;
                    if (dmask & (1u << s))              // hermitized onsite
                        ax = on[p13 + q] * fpq + on[q * NORB + p] * fqp;
                    int i1 = ci1[s];
                    for (int it = ci0[s]; it < i1; ++it) {
                        int ent = elist[it];
                        const float* h = hopping + (size_t)(ent >> 8) * NORB2;
                        float hv = (ent & 1) ? h[q * NORB + p] * fqp
                                             : h[p13 + q] * fpq;
                        ax += phc[it] * hv;
                        ay += phs[it] * hv;
                    }
                    v[2 * u] = ax; v[2 * u + 1] = ay;
                }
                size_t ci = rb + (size_t)p * ld + c0;   // even
                if (es == 2) {
                    ((fx4*)out)[ci >> 1] = (fx4){v[0], v[1], v[2], v[3]};
                } else {
                    ((fx2*)out)[ci >> 1] = (fx2){v[0], v[2]};
                }
            }
        }
    }
}

extern "C" void kernel_launch(void* const* d_in, const int* in_sizes, int n_in,
                              void* d_out, int out_size, void* d_ws, size_t ws_size,
                              hipStream_t stream) {
    const float* hopping    = (const float*)d_in[0];
    const float* onsite     = (const float*)d_in[1];
    const float* kpoints    = (const float*)d_in[2];
    const float* cell_shift = (const float*)d_in[3];
    const int*   edge_index = (const int*)d_in[4];
    float* out = (float*)d_out;

    int E = in_sizes[0] / NORB2;   // 2048
    int N = in_sizes[1] / NORB2;   // 128
    int K = in_sizes[2] / 3;       // 16
    int ld = N * NORB;             // 1664

    size_t full = (size_t)K * ld * ld * 2;
    int es = ((size_t)out_size >= full) ? 2 : 1;

    int nwg = N * K;               // 2048 WGs, one sequential 173 KB block each
    k_fused<<<nwg, NTHR, 0, stream>>>(hopping, onsite, kpoints, cell_shift,
                                      edge_index, out, N, E, K, ld, es);
}